// Round 11
// baseline (294.196 us; speedup 1.0000x reference)
//
#include <hip/hip_runtime.h>
#include <stdint.h>
#include <float.h>

#define NUM_SAMPLES 50
#define EPSF 1e-8f
#define PENALTY 1e-4f
#define REV_SCALE 0.1f

// grid 1: original vertices (N(0,1) coords). G=32: ring machinery vs streaming
// balance point measured in R9->R10 (48->32 = -13us on query).
#define G1 32
#define G1LO -5.0f
#define G1HI 5.0f
#define NCELL1 (G1*G1*G1)
// grid 2: original-face barycenters (sigma ~0.577)
#define G2 32
#define G2LO -3.5f
#define G2HI 3.5f
#define NCELL2 (G2*G2*G2)

#define NTOTALL (NCELL1 + NCELL2)            // 65536
#define SCAN_BLOCKS (NTOTALL / 1024)         // 64
static_assert(NTOTALL % 1024 == 0, "scan tiling");

// GS=16 at G=32: ~38 pts/central-cell -> 2.4 trips/cell (vs 4.75 at GS=8);
// streaming now dominates machinery, so wider groups win (GS sweep at G=48
// favored 8, but that was the 11-pt/cell machinery-bound regime).
#define GS 16
#define QBLOCKS 8192   // 8192 x 16 groups = 131K slots, ~2 passes over 255K queries

// acc region layout (floats): fwd slots [0..1023] stride 16; rev slots [1024..2047];
// max slots (int bits) [2048..3071]; done counter (int) at [3072]. 4096 floats = 16 KB.
#define ACC_FLOATS 4096

// ---------------- JAX threefry2x32 (exact) ----------------
__device__ __forceinline__ uint32_t rotl32(uint32_t v, int d) {
  return (v << d) | (v >> (32 - d));
}

__device__ __forceinline__ void threefry2x32(uint32_t k0, uint32_t k1,
                                             uint32_t x0, uint32_t x1,
                                             uint32_t& o0, uint32_t& o1) {
  const uint32_t k2 = k0 ^ k1 ^ 0x1BD11BDAu;
  x0 += k0; x1 += k1;
#define TF_ROUND(r) { x0 += x1; x1 = rotl32(x1, (r)); x1 ^= x0; }
  TF_ROUND(13) TF_ROUND(15) TF_ROUND(26) TF_ROUND(6)
  x0 += k1; x1 += k2 + 1u;
  TF_ROUND(17) TF_ROUND(29) TF_ROUND(16) TF_ROUND(24)
  x0 += k2; x1 += k0 + 2u;
  TF_ROUND(13) TF_ROUND(15) TF_ROUND(26) TF_ROUND(6)
  x0 += k0; x1 += k1 + 3u;
  TF_ROUND(17) TF_ROUND(29) TF_ROUND(16) TF_ROUND(24)
  x0 += k1; x1 += k2 + 4u;
  TF_ROUND(13) TF_ROUND(15) TF_ROUND(26) TF_ROUND(6)
  x0 += k2; x1 += k0 + 5u;
#undef TF_ROUND
  o0 = x0; o1 = x1;
}

__device__ __forceinline__ float bits_to_uniform(uint32_t bits) {
  return __uint_as_float((bits >> 9) | 0x3f800000u) - 1.0f;
}

__device__ __forceinline__ float jax_uniform_at(uint32_t k0, uint32_t k1, uint32_t idx) {
  uint32_t o0, o1;
  threefry2x32(k0, k1, 0u, idx, o0, o1);
  return bits_to_uniform(o0 ^ o1);
}

__device__ __forceinline__ int cell_coord(float p, float lo, float invh, int G) {
  int i = (int)floorf((p - lo) * invh);
  return min(max(i, 0), G - 1);
}

// sample id -> position + weight (exact JAX RNG; partitionable split of key(42))
__device__ __forceinline__ float4 gen_sample(int id, const float* __restrict__ sv,
                                             const int* __restrict__ sfc,
                                             const float* __restrict__ fp, int NFP) {
  int face = id / NUM_SAMPLES;
  uint32_t a0, a1, b0, b1;
  threefry2x32(0u, 42u, 0u, 0u, a0, a1);  // rk1 (constant-folds)
  threefry2x32(0u, 42u, 0u, 1u, b0, b1);  // rk2 (constant-folds)
  float r1 = jax_uniform_at(a0, a1, (uint32_t)id);
  float r2 = jax_uniform_at(b0, b1, (uint32_t)id);
  float sr1 = sqrtf(r1);
  float ca = 1.0f - sr1;
  float cb = sr1 * (1.0f - r2);
  float cc = sr1 * r2;
  int va = sfc[3*face], vb = sfc[3*face+1], vc = sfc[3*face+2];
  float px = ca*sv[3*va]   + cb*sv[3*vb]   + cc*sv[3*vc];
  float py = ca*sv[3*va+1] + cb*sv[3*vb+1] + cc*sv[3*vc+1];
  float pz = ca*sv[3*va+2] + cb*sv[3*vb+2] + cc*sv[3*vc+2];
  float w = (face < NFP) ? fp[face] : 0.0f;
  return make_float4(px, py, pz, w);
}

// ---------------- prep: barycenters + vertex float4 + histograms (2 grids, 85K items)
__global__ __launch_bounds__(256) void prep_kernel(
    const float* __restrict__ ov, const int* __restrict__ ofc,
    const float* __restrict__ sv, const int* __restrict__ sfc,
    float4* __restrict__ ob4, float4* __restrict__ sb4, float4* __restrict__ ov4,
    int* __restrict__ cnt, int NOF, int NSF, int NOV) {
  int i = blockIdx.x * blockDim.x + threadIdx.x;
  if (i >= NOF + NSF + NOV) return;
  if (i < NOF) {
    int a = ofc[3*i], b = ofc[3*i+1], c = ofc[3*i+2];
    float x = (ov[3*a]   + ov[3*b]   + ov[3*c])   / 3.0f;
    float y = (ov[3*a+1] + ov[3*b+1] + ov[3*c+1]) / 3.0f;
    float z = (ov[3*a+2] + ov[3*b+2] + ov[3*c+2]) / 3.0f;
    ob4[i] = make_float4(x, y, z, x*x + y*y + z*z);
    const float invh = (float)G2 / (G2HI - G2LO);
    int cx = cell_coord(x, G2LO, invh, G2);
    int cy = cell_coord(y, G2LO, invh, G2);
    int cz = cell_coord(z, G2LO, invh, G2);
    atomicAdd(&cnt[NCELL1 + (cz*G2 + cy)*G2 + cx], 1);
  } else if (i < NOF + NSF) {
    int j = i - NOF;
    int a = sfc[3*j], b = sfc[3*j+1], c = sfc[3*j+2];
    float x = (sv[3*a]   + sv[3*b]   + sv[3*c])   / 3.0f;
    float y = (sv[3*a+1] + sv[3*b+1] + sv[3*c+1]) / 3.0f;
    float z = (sv[3*a+2] + sv[3*b+2] + sv[3*c+2]) / 3.0f;
    sb4[j] = make_float4(x, y, z, x*x + y*y + z*z);
  } else {
    int j = i - NOF - NSF;
    float x = ov[3*j], y = ov[3*j+1], z = ov[3*j+2];
    ov4[j] = make_float4(x, y, z, x*x + y*y + z*z);
    const float invh = (float)G1 / (G1HI - G1LO);
    int cx = cell_coord(x, G1LO, invh, G1);
    int cy = cell_coord(y, G1LO, invh, G1);
    int cz = cell_coord(z, G1LO, invh, G1);
    atomicAdd(&cnt[(cz*G1 + cy)*G1 + cx], 1);
  }
}

// ---------------- fused parallel scan (publish aggregate + load-only poll)
// All SCAN_BLOCKS=64 blocks are co-resident on 256 CUs -> no deadlock.
__global__ __launch_bounds__(256) void scan_kernel(
    const int4* __restrict__ cnt4, unsigned long long* __restrict__ gsum,
    int* __restrict__ cs, int* __restrict__ cur) {
  __shared__ int lds[256];
  __shared__ int wsum[4];
  __shared__ int boffS;
  int t = threadIdx.x;
  int gid = blockIdx.x * 256 + t;
  int4 c = cnt4[gid];
  int s01 = c.x + c.y;
  int tsum = s01 + c.z + c.w;
  lds[t] = tsum;
  __syncthreads();
  for (int d = 1; d < 256; d <<= 1) {
    int u = (t >= d) ? lds[t - d] : 0;
    __syncthreads();
    lds[t] += u;
    __syncthreads();
  }
  int incl = lds[t];
  int agg  = lds[255];
  if (t == 0)
    atomicExch(&gsum[blockIdx.x], (1ULL << 63) | (unsigned long long)(unsigned)agg);
  int pre = 0;
  if (t < (int)blockIdx.x) {
    unsigned long long v;
    while (!((v = __hip_atomic_load(&gsum[t], __ATOMIC_RELAXED,
                                    __HIP_MEMORY_SCOPE_AGENT)) >> 63)) { }
    pre = (int)(v & 0xFFFFFFFFULL);
  }
  for (int o = 32; o > 0; o >>= 1) pre += __shfl_down(pre, o);
  if ((t & 63) == 0) wsum[t >> 6] = pre;
  __syncthreads();
  if (t == 0) boffS = wsum[0] + wsum[1] + wsum[2] + wsum[3];
  __syncthreads();
  int base = boffS + incl - tsum;
  int4 o4;
  o4.x = base;
  o4.y = base + c.x;
  o4.z = base + s01;
  o4.w = base + s01 + c.z;
  ((int4*)cs)[gid] = o4;
  ((int4*)cur)[gid] = o4;
  if (blockIdx.x == gridDim.x - 1 && t == 255) cs[NTOTALL] = boffS + incl;
}

// ---------------- scatter vertices + barycenters into cell-sorted order (50K items)
__global__ __launch_bounds__(256) void scatter_kernel(
    const float4* __restrict__ ov4, const float4* __restrict__ ob4,
    int* __restrict__ cur, float4* __restrict__ sorted, int NOV, int NOF) {
  int i = blockIdx.x * blockDim.x + threadIdx.x;
  if (i >= NOV + NOF) return;
  float4 p; int c;
  if (i < NOV) {
    p = ov4[i];
    const float invh = (float)G1 / (G1HI - G1LO);
    int cx = cell_coord(p.x, G1LO, invh, G1);
    int cy = cell_coord(p.y, G1LO, invh, G1);
    int cz = cell_coord(p.z, G1LO, invh, G1);
    c = (cz*G1 + cy)*G1 + cx;
  } else {
    p = ob4[i - NOV];
    const float invh = (float)G2 / (G2HI - G2LO);
    int cx = cell_coord(p.x, G2LO, invh, G2);
    int cy = cell_coord(p.y, G2LO, invh, G2);
    int cz = cell_coord(p.z, G2LO, invh, G2);
    c = NCELL1 + (cz*G2 + cy)*G2 + cx;
  }
  int idx = atomicAdd(&cur[c], 1);
  sorted[idx] = p;
}

// ---------------- cooperative GS-lane exact 1-NN (group-uniform control flow)
__device__ __forceinline__ float group_min(float v) {
  for (int o = GS / 2; o > 0; o >>= 1) v = fminf(v, __shfl_xor(v, o, GS));
  return v;
}

// Exact 1-NN with wall-distance-tightened ring break + per-row/per-cell pruning.
__device__ float nn_group(float px, float py, float pz, float q2,
                          const int* __restrict__ cs, const float4* __restrict__ pts,
                          int G, float lo, float h, int cellofs, int lane) {
  const float invh = 1.0f / h;
  int ix = cell_coord(px, lo, invh, G);
  int iy = cell_coord(py, lo, invh, G);
  int iz = cell_coord(pz, lo, invh, G);
  float wxm = fmaxf(px - (lo + (float)ix * h), 0.0f);
  float wxp = fmaxf((lo + (float)(ix + 1) * h) - px, 0.0f);
  float wym = fmaxf(py - (lo + (float)iy * h), 0.0f);
  float wyp = fmaxf((lo + (float)(iy + 1) * h) - py, 0.0f);
  float wzm = fmaxf(pz - (lo + (float)iz * h), 0.0f);
  float wzp = fmaxf((lo + (float)(iz + 1) * h) - pz, 0.0f);
  float wmin = fminf(fminf(fminf(wxm, wxp), fminf(wym, wyp)), fminf(wzm, wzp));

  float m2x = -2.0f*px, m2y = -2.0f*py, m2z = -2.0f*pz;
  float best = FLT_MAX;  // per-lane partial of (|v|^2 - 2 p.v) = d^2 - q2
  for (int r = 0; r < G; ++r) {
    float bmin = group_min(best);
    float bestd2 = bmin + q2;
    if (r >= 1) {
      float bd = (float)(r - 1) * h + wmin;
      if (bestd2 <= bd * bd) break;
    }
    int z0 = max(iz - r, 0), z1 = min(iz + r, G - 1);
    int y0 = max(iy - r, 0), y1 = min(iy + r, G - 1);
    int x0 = max(ix - r, 0), x1 = min(ix + r, G - 1);
    float dxm = (float)(r - 1) * h + wxm;
    float dxp = (float)(r - 1) * h + wxp;
    for (int zz = z0; zz <= z1; ++zz) {
      int oz = zz - iz;
      int adz = abs(oz);
      float dz = (oz > 0) ? (float)(oz - 1) * h + wzp
               : (oz < 0) ? (float)(-oz - 1) * h + wzm : 0.0f;
      float dz2 = dz * dz;
      if (dz2 >= bestd2) continue;
      for (int yy = y0; yy <= y1; ++yy) {
        int oy = yy - iy;
        int ady = abs(oy);
        float dy = (oy > 0) ? (float)(oy - 1) * h + wyp
                 : (oy < 0) ? (float)(-oy - 1) * h + wym : 0.0f;
        float rowd2 = dz2 + dy * dy;
        if (rowd2 >= bestd2) continue;
        int rowbase = cellofs + (zz*G + yy)*G;
        if (adz == r || ady == r) {
          int s = cs[rowbase + x0];
          int e = cs[rowbase + x1 + 1];
          for (int i = s + lane; i < e; i += GS) {
            float4 v = pts[i];
            best = fminf(best, fmaf(v.z, m2z, fmaf(v.y, m2y, fmaf(v.x, m2x, v.w))));
          }
        } else {
          if (ix - r >= 0 && rowd2 + dxm * dxm < bestd2) {
            int cc = rowbase + ix - r;
            int s = cs[cc], e = cs[cc + 1];
            for (int i = s + lane; i < e; i += GS) {
              float4 v = pts[i];
              best = fminf(best, fmaf(v.z, m2z, fmaf(v.y, m2y, fmaf(v.x, m2x, v.w))));
            }
          }
          if (r > 0 && ix + r <= G - 1 && rowd2 + dxp * dxp < bestd2) {
            int cc = rowbase + ix + r;
            int s = cs[cc], e = cs[cc + 1];
            for (int i = s + lane; i < e; i += GS) {
              float4 v = pts[i];
              best = fminf(best, fmaf(v.z, m2z, fmaf(v.y, m2y, fmaf(v.x, m2x, v.w))));
            }
          }
        }
      }
    }
  }
  return group_min(best);
}

// ---------------- fused queries (grid-stride; samples generated on the fly) + final
__global__ __launch_bounds__(256) void query_kernel(
    const float* __restrict__ fp, const float4* __restrict__ sb4,
    const float* __restrict__ sv, const int* __restrict__ sfc,
    const int* __restrict__ cs, const float4* __restrict__ sorted,
    float* __restrict__ acc, float* __restrict__ out,
    int NSF, int NFP, int nsamp) {
  const float h1 = (G1HI - G1LO) / (float)G1;
  const float h2 = (G2HI - G2LO) / (float)G2;
  int lane = threadIdx.x & (GS - 1);
  int grpInBlk = threadIdx.x / GS;
  const int grpsPerBlk = 256 / GS;       // 16
  int totalGroups = NSF + nsamp;
  float facc = 0.0f, racc = 0.0f, rmaxv = 0.0f;
  for (int g = blockIdx.x * grpsPerBlk + grpInBlk; g < totalGroups;
       g += gridDim.x * grpsPerBlk) {
    if (g < NSF) {
      float4 s = sb4[g];
      float best = nn_group(s.x, s.y, s.z, s.w, cs, sorted, G2, G2LO, h2, NCELL1, lane);
      if (lane == 0) {
        float mind = sqrtf(fmaxf(best + s.w, 0.0f));
        float p = (g < NFP) ? fp[g] : 0.0f;
        facc += p * mind;
      }
    } else {
      int sid = g - NSF;
      float4 s = gen_sample(sid, sv, sfc, fp, NFP);  // exact same bits as staged path
      float q2 = s.x*s.x + s.y*s.y + s.z*s.z;
      float best = nn_group(s.x, s.y, s.z, q2, cs, sorted, G1, G1LO, h1, 0, lane);
      if (lane == 0) {
        float d = sqrtf(fmaxf(best + q2, 0.0f));
        racc += s.w * d;
        rmaxv = fmaxf(rmaxv, d);
      }
    }
  }
  // block reduce (non-leader lanes hold 0)
  __shared__ float sF[4], sR[4], sM[4];
  __shared__ int isLast;
  __shared__ float stash[4];
  for (int o = 32; o > 0; o >>= 1) {
    facc += __shfl_down(facc, o);
    racc += __shfl_down(racc, o);
    rmaxv = fmaxf(rmaxv, __shfl_down(rmaxv, o));
  }
  int wid = threadIdx.x >> 6;
  if ((threadIdx.x & 63) == 0) { sF[wid] = facc; sR[wid] = racc; sM[wid] = rmaxv; }
  __syncthreads();
  if (threadIdx.x == 0) {
    float tf = sF[0] + sF[1] + sF[2] + sF[3];
    float tr = sR[0] + sR[1] + sR[2] + sR[3];
    float tm = fmaxf(fmaxf(sM[0], sM[1]), fmaxf(sM[2], sM[3]));
    int slot = (blockIdx.x & 63) * 16;
    atomicAdd(&acc[slot], tf);
    atomicAdd(&acc[1024 + slot], tr);
    atomicMax((int*)acc + 2048 + slot, __float_as_int(tm));
    __threadfence();
    int old = atomicAdd((int*)acc + 3072, 1);
    isLast = (old == (int)gridDim.x - 1) ? 1 : 0;
  }
  __syncthreads();
  if (!isLast) return;

  // ---- final: last block reads slots coherently via atomic RMWs ----
  __shared__ float red[256];
  int t = threadIdx.x;
  float fsum = 0.0f, rsum = 0.0f, rmx = 0.0f;
  if (t < 64)        fsum = atomicAdd(&acc[t * 16], 0.0f);
  else if (t < 128)  rsum = atomicAdd(&acc[1024 + (t - 64) * 16], 0.0f);
  else if (t < 192)  rmx  = __int_as_float(atomicMax((int*)acc + 2048 + (t - 128) * 16, 0));
  float sfp = 0.0f;
  for (int i = t; i < NSF; i += 256) sfp += (i < NFP) ? fp[i] : 0.0f;

  red[t] = fsum; __syncthreads();
  for (int o = 128; o > 0; o >>= 1) { if (t < o) red[t] += red[t + o]; __syncthreads(); }
  if (t == 0) stash[0] = red[0];
  __syncthreads();
  red[t] = rsum; __syncthreads();
  for (int o = 128; o > 0; o >>= 1) { if (t < o) red[t] += red[t + o]; __syncthreads(); }
  if (t == 0) stash[1] = red[0];
  __syncthreads();
  red[t] = rmx; __syncthreads();
  for (int o = 128; o > 0; o >>= 1) { if (t < o) red[t] = fmaxf(red[t], red[t + o]); __syncthreads(); }
  if (t == 0) stash[2] = red[0];
  __syncthreads();
  red[t] = sfp; __syncthreads();
  for (int o = 128; o > 0; o >>= 1) { if (t < o) red[t] += red[t + o]; __syncthreads(); }
  if (t == 0) {
    float fwd = stash[0] + PENALTY * ((float)NSF - red[0]);
    float rev = stash[1] * (REV_SCALE / (stash[2] + EPSF));
    out[0] = fwd + rev;
  }
}

extern "C" void kernel_launch(void* const* d_in, const int* in_sizes, int n_in,
                              void* d_out, int out_size, void* d_ws, size_t ws_size,
                              hipStream_t stream) {
  const float* ov  = (const float*)d_in[0];
  const int*   ofc = (const int*)  d_in[1];
  const float* sv  = (const float*)d_in[2];
  const int*   sfc = (const int*)  d_in[3];
  const float* fp  = (const float*)d_in[4];
  float* out = (float*)d_out;

  int NOV = in_sizes[0] / 3;
  int NOF = in_sizes[1] / 3;
  int NSF = in_sizes[3] / 3;
  int NFP = in_sizes[4];
  int nsamp = NSF * NUM_SAMPLES;

  // ws layout: [acc 16KB][gsum 2KB][cnt][cs][cur][float4 arrays]
  char* w = (char*)d_ws;
  float* acc = (float*)w;                       w += ACC_FLOATS * 4;       // 16 KB
  unsigned long long* gsum = (unsigned long long*)w; w += 2048;            // 2 KB
  int*   cnt = (int*)w;                         w += (size_t)NTOTALL * 4;
  size_t zeroBytes = (size_t)(w - (char*)d_ws); // acc + gsum + cnt, contiguous
  int*   cs  = (int*)w;                         w += (size_t)(NTOTALL + 16) * 4;
  int*   cur = (int*)w;                         w += (size_t)NTOTALL * 4;
  float4* ob4    = (float4*)w;  w += (size_t)NOF * 16;
  float4* sb4    = (float4*)w;  w += (size_t)NSF * 16;
  float4* ov4    = (float4*)w;  w += (size_t)NOV * 16;
  float4* sorted = (float4*)w;  w += (size_t)(NOV + NOF) * 16;

  hipMemsetAsync(d_ws, 0, zeroBytes, stream);

  int total = NOF + NSF + NOV;
  hipLaunchKernelGGL(prep_kernel, dim3((total + 255) / 256), dim3(256), 0, stream,
                     ov, ofc, sv, sfc, ob4, sb4, ov4, cnt, NOF, NSF, NOV);

  hipLaunchKernelGGL(scan_kernel, dim3(SCAN_BLOCKS), dim3(256), 0, stream,
                     (const int4*)cnt, gsum, cs, cur);

  hipLaunchKernelGGL(scatter_kernel, dim3((NOV + NOF + 255) / 256), dim3(256), 0, stream,
                     ov4, ob4, cur, sorted, NOV, NOF);

  hipLaunchKernelGGL(query_kernel, dim3(QBLOCKS), dim3(256), 0, stream,
                     fp, sb4, sv, sfc, cs, sorted, acc, out, NSF, NFP, nsamp);
}

// Round 12
// 209.259 us; speedup vs baseline: 1.4059x; 1.4059x over previous
//
#include <hip/hip_runtime.h>
#include <stdint.h>
#include <float.h>

#define NUM_SAMPLES 50
#define EPSF 1e-8f
#define PENALTY 1e-4f
#define REV_SCALE 0.1f

// grid 1: original vertices (N(0,1) coords). G=32 measured best (R9->R10).
#define G1 32
#define G1LO -5.0f
#define G1HI 5.0f
#define NCELL1 (G1*G1*G1)
// grid 2: original-face barycenters (sigma ~0.577)
#define G2 32
#define G2LO -3.5f
#define G2HI 3.5f
#define NCELL2 (G2*G2*G2)

#define NTOTALL (NCELL1 + NCELL2)            // 65536
#define SCAN_BLOCKS (NTOTALL / 1024)         // 64
static_assert(NTOTALL % 1024 == 0, "scan tiling");

#define GS 8           // lanes per query group (GS sweep: 16->172/220, 8->150, 1->182)
#define QBLOCKS 4096   // query grid (measured best R10)

// acc region layout (floats): fwd slots [0..1023] stride 16; rev slots [1024..2047];
// max slots (int bits) [2048..3071]; done counter (int) at [3072]. 4096 floats = 16 KB.
#define ACC_FLOATS 4096

// ---------------- JAX threefry2x32 (exact) ----------------
__device__ __forceinline__ uint32_t rotl32(uint32_t v, int d) {
  return (v << d) | (v >> (32 - d));
}

__device__ __forceinline__ void threefry2x32(uint32_t k0, uint32_t k1,
                                             uint32_t x0, uint32_t x1,
                                             uint32_t& o0, uint32_t& o1) {
  const uint32_t k2 = k0 ^ k1 ^ 0x1BD11BDAu;
  x0 += k0; x1 += k1;
#define TF_ROUND(r) { x0 += x1; x1 = rotl32(x1, (r)); x1 ^= x0; }
  TF_ROUND(13) TF_ROUND(15) TF_ROUND(26) TF_ROUND(6)
  x0 += k1; x1 += k2 + 1u;
  TF_ROUND(17) TF_ROUND(29) TF_ROUND(16) TF_ROUND(24)
  x0 += k2; x1 += k0 + 2u;
  TF_ROUND(13) TF_ROUND(15) TF_ROUND(26) TF_ROUND(6)
  x0 += k0; x1 += k1 + 3u;
  TF_ROUND(17) TF_ROUND(29) TF_ROUND(16) TF_ROUND(24)
  x0 += k1; x1 += k2 + 4u;
  TF_ROUND(13) TF_ROUND(15) TF_ROUND(26) TF_ROUND(6)
  x0 += k2; x1 += k0 + 5u;
#undef TF_ROUND
  o0 = x0; o1 = x1;
}

__device__ __forceinline__ float bits_to_uniform(uint32_t bits) {
  return __uint_as_float((bits >> 9) | 0x3f800000u) - 1.0f;
}

__device__ __forceinline__ float jax_uniform_at(uint32_t k0, uint32_t k1, uint32_t idx) {
  uint32_t o0, o1;
  threefry2x32(k0, k1, 0u, idx, o0, o1);
  return bits_to_uniform(o0 ^ o1);
}

__device__ __forceinline__ int cell_coord(float p, float lo, float invh, int G) {
  int i = (int)floorf((p - lo) * invh);
  return min(max(i, 0), G - 1);
}

// sample id -> position + weight (exact JAX RNG; partitionable split of key(42))
__device__ __forceinline__ float4 gen_sample(int id, const float* __restrict__ sv,
                                             const int* __restrict__ sfc,
                                             const float* __restrict__ fp, int NFP) {
  int face = id / NUM_SAMPLES;
  uint32_t a0, a1, b0, b1;
  threefry2x32(0u, 42u, 0u, 0u, a0, a1);  // rk1 (constant-folds)
  threefry2x32(0u, 42u, 0u, 1u, b0, b1);  // rk2 (constant-folds)
  float r1 = jax_uniform_at(a0, a1, (uint32_t)id);
  float r2 = jax_uniform_at(b0, b1, (uint32_t)id);
  float sr1 = sqrtf(r1);
  float ca = 1.0f - sr1;
  float cb = sr1 * (1.0f - r2);
  float cc = sr1 * r2;
  int va = sfc[3*face], vb = sfc[3*face+1], vc = sfc[3*face+2];
  float px = ca*sv[3*va]   + cb*sv[3*vb]   + cc*sv[3*vc];
  float py = ca*sv[3*va+1] + cb*sv[3*vb+1] + cc*sv[3*vc+1];
  float pz = ca*sv[3*va+2] + cb*sv[3*vb+2] + cc*sv[3*vc+2];
  float w = (face < NFP) ? fp[face] : 0.0f;
  return make_float4(px, py, pz, w);
}

// ---------------- prep: barycenters + vertex float4 + histograms (2 grids, 85K items)
__global__ __launch_bounds__(256) void prep_kernel(
    const float* __restrict__ ov, const int* __restrict__ ofc,
    const float* __restrict__ sv, const int* __restrict__ sfc,
    float4* __restrict__ ob4, float4* __restrict__ sb4, float4* __restrict__ ov4,
    int* __restrict__ cnt, int NOF, int NSF, int NOV) {
  int i = blockIdx.x * blockDim.x + threadIdx.x;
  if (i >= NOF + NSF + NOV) return;
  if (i < NOF) {
    int a = ofc[3*i], b = ofc[3*i+1], c = ofc[3*i+2];
    float x = (ov[3*a]   + ov[3*b]   + ov[3*c])   / 3.0f;
    float y = (ov[3*a+1] + ov[3*b+1] + ov[3*c+1]) / 3.0f;
    float z = (ov[3*a+2] + ov[3*b+2] + ov[3*c+2]) / 3.0f;
    ob4[i] = make_float4(x, y, z, x*x + y*y + z*z);
    const float invh = (float)G2 / (G2HI - G2LO);
    int cx = cell_coord(x, G2LO, invh, G2);
    int cy = cell_coord(y, G2LO, invh, G2);
    int cz = cell_coord(z, G2LO, invh, G2);
    atomicAdd(&cnt[NCELL1 + (cz*G2 + cy)*G2 + cx], 1);
  } else if (i < NOF + NSF) {
    int j = i - NOF;
    int a = sfc[3*j], b = sfc[3*j+1], c = sfc[3*j+2];
    float x = (sv[3*a]   + sv[3*b]   + sv[3*c])   / 3.0f;
    float y = (sv[3*a+1] + sv[3*b+1] + sv[3*c+1]) / 3.0f;
    float z = (sv[3*a+2] + sv[3*b+2] + sv[3*c+2]) / 3.0f;
    sb4[j] = make_float4(x, y, z, x*x + y*y + z*z);
  } else {
    int j = i - NOF - NSF;
    float x = ov[3*j], y = ov[3*j+1], z = ov[3*j+2];
    ov4[j] = make_float4(x, y, z, x*x + y*y + z*z);
    const float invh = (float)G1 / (G1HI - G1LO);
    int cx = cell_coord(x, G1LO, invh, G1);
    int cy = cell_coord(y, G1LO, invh, G1);
    int cz = cell_coord(z, G1LO, invh, G1);
    atomicAdd(&cnt[(cz*G1 + cy)*G1 + cx], 1);
  }
}

// ---------------- fused parallel scan (publish aggregate + load-only poll)
__global__ __launch_bounds__(256) void scan_kernel(
    const int4* __restrict__ cnt4, unsigned long long* __restrict__ gsum,
    int* __restrict__ cs, int* __restrict__ cur) {
  __shared__ int lds[256];
  __shared__ int wsum[4];
  __shared__ int boffS;
  int t = threadIdx.x;
  int gid = blockIdx.x * 256 + t;
  int4 c = cnt4[gid];
  int s01 = c.x + c.y;
  int tsum = s01 + c.z + c.w;
  lds[t] = tsum;
  __syncthreads();
  for (int d = 1; d < 256; d <<= 1) {
    int u = (t >= d) ? lds[t - d] : 0;
    __syncthreads();
    lds[t] += u;
    __syncthreads();
  }
  int incl = lds[t];
  int agg  = lds[255];
  if (t == 0)
    atomicExch(&gsum[blockIdx.x], (1ULL << 63) | (unsigned long long)(unsigned)agg);
  int pre = 0;
  if (t < (int)blockIdx.x) {
    unsigned long long v;
    while (!((v = __hip_atomic_load(&gsum[t], __ATOMIC_RELAXED,
                                    __HIP_MEMORY_SCOPE_AGENT)) >> 63)) { }
    pre = (int)(v & 0xFFFFFFFFULL);
  }
  for (int o = 32; o > 0; o >>= 1) pre += __shfl_down(pre, o);
  if ((t & 63) == 0) wsum[t >> 6] = pre;
  __syncthreads();
  if (t == 0) boffS = wsum[0] + wsum[1] + wsum[2] + wsum[3];
  __syncthreads();
  int base = boffS + incl - tsum;
  int4 o4;
  o4.x = base;
  o4.y = base + c.x;
  o4.z = base + s01;
  o4.w = base + s01 + c.z;
  ((int4*)cs)[gid] = o4;
  ((int4*)cur)[gid] = o4;
  if (blockIdx.x == gridDim.x - 1 && t == 255) cs[NTOTALL] = boffS + incl;
}

// ---------------- scatter vertices + barycenters into cell-sorted order (50K items)
__global__ __launch_bounds__(256) void scatter_kernel(
    const float4* __restrict__ ov4, const float4* __restrict__ ob4,
    int* __restrict__ cur, float4* __restrict__ sorted, int NOV, int NOF) {
  int i = blockIdx.x * blockDim.x + threadIdx.x;
  if (i >= NOV + NOF) return;
  float4 p; int c;
  if (i < NOV) {
    p = ov4[i];
    const float invh = (float)G1 / (G1HI - G1LO);
    int cx = cell_coord(p.x, G1LO, invh, G1);
    int cy = cell_coord(p.y, G1LO, invh, G1);
    int cz = cell_coord(p.z, G1LO, invh, G1);
    c = (cz*G1 + cy)*G1 + cx;
  } else {
    p = ob4[i - NOV];
    const float invh = (float)G2 / (G2HI - G2LO);
    int cx = cell_coord(p.x, G2LO, invh, G2);
    int cy = cell_coord(p.y, G2LO, invh, G2);
    int cz = cell_coord(p.z, G2LO, invh, G2);
    c = NCELL1 + (cz*G2 + cy)*G2 + cx;
  }
  int idx = atomicAdd(&cur[c], 1);
  sorted[idx] = p;
}

// ---------------- cooperative GS-lane exact 1-NN (group-uniform control flow)
__device__ __forceinline__ float group_min(float v) {
  for (int o = GS / 2; o > 0; o >>= 1) v = fminf(v, __shfl_xor(v, o, GS));
  return v;
}

// Exact 1-NN. Fast path: 3x3x3 neighborhood as 9 contiguous row-spans with all
// 18 cs loads issued up front (1 latency round, not 9 serial), central row
// first, then row-level pruning. Clamped-duplicate rows are covered by the
// central row (prune-safe) and re-evaluation is idempotent under fminf.
// Fallback (rare: best > (h+wmin)^2): exact ring walk from r=2.
__device__ float nn_group(float px, float py, float pz, float q2,
                          const int* __restrict__ cs, const float4* __restrict__ pts,
                          int G, float lo, float h, int cellofs, int lane) {
  const float invh = 1.0f / h;
  int ix = cell_coord(px, lo, invh, G);
  int iy = cell_coord(py, lo, invh, G);
  int iz = cell_coord(pz, lo, invh, G);
  float wxm = fmaxf(px - (lo + (float)ix * h), 0.0f);
  float wxp = fmaxf((lo + (float)(ix + 1) * h) - px, 0.0f);
  float wym = fmaxf(py - (lo + (float)iy * h), 0.0f);
  float wyp = fmaxf((lo + (float)(iy + 1) * h) - py, 0.0f);
  float wzm = fmaxf(pz - (lo + (float)iz * h), 0.0f);
  float wzp = fmaxf((lo + (float)(iz + 1) * h) - pz, 0.0f);
  float wmin = fminf(fminf(fminf(wxm, wxp), fminf(wym, wyp)), fminf(wzm, wzp));

  float m2x = -2.0f*px, m2y = -2.0f*py, m2z = -2.0f*pz;
  float best = FLT_MAX;  // per-lane partial of (|v|^2 - 2 p.v) = d^2 - q2

  int x0 = max(ix - 1, 0), x1 = min(ix + 1, G - 1);

  // ---- fast path: 9 row-spans, all loads issued before any streaming ----
  int   sA[9], eA[9];
  float rb2[9];
  {
    const float dzo0 = wzm, dzo2 = wzp;
    const float dyo0 = wym, dyo2 = wyp;
#pragma unroll
    for (int k = 0; k < 9; ++k) {
      const int dzi = k / 3, dyi = k % 3;                   // 0,1,2 (compile-time)
      int zz = min(max(iz + dzi - 1, 0), G - 1);
      int yy = min(max(iy + dyi - 1, 0), G - 1);
      int rowbase = cellofs + (zz * G + yy) * G;
      sA[k] = cs[rowbase + x0];
      eA[k] = cs[rowbase + x1 + 1];
      float dz = (dzi == 0) ? dzo0 : (dzi == 2) ? dzo2 : 0.0f;
      float dy = (dyi == 0) ? dyo0 : (dyi == 2) ? dyo2 : 0.0f;
      rb2[k] = dz * dz + dy * dy;
    }
  }
  // central row first (k=4): establishes best
  for (int i = sA[4] + lane; i < eA[4]; i += GS) {
    float4 v = pts[i];
    best = fminf(best, fmaf(v.z, m2z, fmaf(v.y, m2y, fmaf(v.x, m2x, v.w))));
  }
  float bmind2 = group_min(best) + q2;   // group-uniform achieved d^2
  // remaining 8 rows, pruned by row lower bound (stale bound: prune-safe)
#pragma unroll
  for (int k = 0; k < 9; ++k) {
    if (k == 4) continue;
    if (rb2[k] < bmind2) {
      for (int i = sA[k] + lane; i < eA[k]; i += GS) {
        float4 v = pts[i];
        best = fminf(best, fmaf(v.z, m2z, fmaf(v.y, m2y, fmaf(v.x, m2x, v.w))));
      }
    }
  }
  float bmin = group_min(best);
  {
    float bd = h + wmin;                 // lower bound for any point in ring >= 2
    if (bmin + q2 <= bd * bd) return bmin;
  }

  // ---- fallback: exact ring walk from r=2 (rare) ----
  best = bmin;                           // all lanes carry the group min now
  for (int r = 2; r < G; ++r) {
    float bestd2 = group_min(best) + q2;
    float bd = (float)(r - 1) * h + wmin;
    if (bestd2 <= bd * bd) break;
    int z0 = max(iz - r, 0), z1 = min(iz + r, G - 1);
    int y0 = max(iy - r, 0), y1 = min(iy + r, G - 1);
    int rx0 = max(ix - r, 0), rx1 = min(ix + r, G - 1);
    float dxm = (float)(r - 1) * h + wxm;
    float dxp = (float)(r - 1) * h + wxp;
    for (int zz = z0; zz <= z1; ++zz) {
      int oz = zz - iz;
      int adz = abs(oz);
      float dz = (oz > 0) ? (float)(oz - 1) * h + wzp
               : (oz < 0) ? (float)(-oz - 1) * h + wzm : 0.0f;
      float dz2 = dz * dz;
      if (dz2 >= bestd2) continue;
      for (int yy = y0; yy <= y1; ++yy) {
        int oy = yy - iy;
        int ady = abs(oy);
        float dy = (oy > 0) ? (float)(oy - 1) * h + wyp
                 : (oy < 0) ? (float)(-oy - 1) * h + wym : 0.0f;
        float rowd2 = dz2 + dy * dy;
        if (rowd2 >= bestd2) continue;
        int rowbase = cellofs + (zz*G + yy)*G;
        if (adz == r || ady == r) {
          int s = cs[rowbase + rx0];
          int e = cs[rowbase + rx1 + 1];
          for (int i = s + lane; i < e; i += GS) {
            float4 v = pts[i];
            best = fminf(best, fmaf(v.z, m2z, fmaf(v.y, m2y, fmaf(v.x, m2x, v.w))));
          }
        } else {
          if (ix - r >= 0 && rowd2 + dxm * dxm < bestd2) {
            int cc = rowbase + ix - r;
            int s = cs[cc], e = cs[cc + 1];
            for (int i = s + lane; i < e; i += GS) {
              float4 v = pts[i];
              best = fminf(best, fmaf(v.z, m2z, fmaf(v.y, m2y, fmaf(v.x, m2x, v.w))));
            }
          }
          if (ix + r <= G - 1 && rowd2 + dxp * dxp < bestd2) {
            int cc = rowbase + ix + r;
            int s = cs[cc], e = cs[cc + 1];
            for (int i = s + lane; i < e; i += GS) {
              float4 v = pts[i];
              best = fminf(best, fmaf(v.z, m2z, fmaf(v.y, m2y, fmaf(v.x, m2x, v.w))));
            }
          }
        }
      }
    }
  }
  return group_min(best);
}

// ---------------- fused queries (grid-stride; samples generated on the fly) + final
__global__ __launch_bounds__(256) void query_kernel(
    const float* __restrict__ fp, const float4* __restrict__ sb4,
    const float* __restrict__ sv, const int* __restrict__ sfc,
    const int* __restrict__ cs, const float4* __restrict__ sorted,
    float* __restrict__ acc, float* __restrict__ out,
    int NSF, int NFP, int nsamp) {
  const float h1 = (G1HI - G1LO) / (float)G1;
  const float h2 = (G2HI - G2LO) / (float)G2;
  int lane = threadIdx.x & (GS - 1);
  int grpInBlk = threadIdx.x / GS;
  const int grpsPerBlk = 256 / GS;       // 32
  int totalGroups = NSF + nsamp;
  float facc = 0.0f, racc = 0.0f, rmaxv = 0.0f;
  for (int g = blockIdx.x * grpsPerBlk + grpInBlk; g < totalGroups;
       g += gridDim.x * grpsPerBlk) {
    if (g < NSF) {
      float4 s = sb4[g];
      float best = nn_group(s.x, s.y, s.z, s.w, cs, sorted, G2, G2LO, h2, NCELL1, lane);
      if (lane == 0) {
        float mind = sqrtf(fmaxf(best + s.w, 0.0f));
        float p = (g < NFP) ? fp[g] : 0.0f;
        facc += p * mind;
      }
    } else {
      int sid = g - NSF;
      float4 s = gen_sample(sid, sv, sfc, fp, NFP);  // exact same bits as staged path
      float q2 = s.x*s.x + s.y*s.y + s.z*s.z;
      float best = nn_group(s.x, s.y, s.z, q2, cs, sorted, G1, G1LO, h1, 0, lane);
      if (lane == 0) {
        float d = sqrtf(fmaxf(best + q2, 0.0f));
        racc += s.w * d;
        rmaxv = fmaxf(rmaxv, d);
      }
    }
  }
  // block reduce (non-leader lanes hold 0)
  __shared__ float sF[4], sR[4], sM[4];
  __shared__ int isLast;
  __shared__ float stash[4];
  for (int o = 32; o > 0; o >>= 1) {
    facc += __shfl_down(facc, o);
    racc += __shfl_down(racc, o);
    rmaxv = fmaxf(rmaxv, __shfl_down(rmaxv, o));
  }
  int wid = threadIdx.x >> 6;
  if ((threadIdx.x & 63) == 0) { sF[wid] = facc; sR[wid] = racc; sM[wid] = rmaxv; }
  __syncthreads();
  if (threadIdx.x == 0) {
    float tf = sF[0] + sF[1] + sF[2] + sF[3];
    float tr = sR[0] + sR[1] + sR[2] + sR[3];
    float tm = fmaxf(fmaxf(sM[0], sM[1]), fmaxf(sM[2], sM[3]));
    int slot = (blockIdx.x & 63) * 16;
    atomicAdd(&acc[slot], tf);
    atomicAdd(&acc[1024 + slot], tr);
    atomicMax((int*)acc + 2048 + slot, __float_as_int(tm));
    __threadfence();
    int old = atomicAdd((int*)acc + 3072, 1);
    isLast = (old == (int)gridDim.x - 1) ? 1 : 0;
  }
  __syncthreads();
  if (!isLast) return;

  // ---- final: last block reads slots coherently via atomic RMWs ----
  __shared__ float red[256];
  int t = threadIdx.x;
  float fsum = 0.0f, rsum = 0.0f, rmx = 0.0f;
  if (t < 64)        fsum = atomicAdd(&acc[t * 16], 0.0f);
  else if (t < 128)  rsum = atomicAdd(&acc[1024 + (t - 64) * 16], 0.0f);
  else if (t < 192)  rmx  = __int_as_float(atomicMax((int*)acc + 2048 + (t - 128) * 16, 0));
  float sfp = 0.0f;
  for (int i = t; i < NSF; i += 256) sfp += (i < NFP) ? fp[i] : 0.0f;

  red[t] = fsum; __syncthreads();
  for (int o = 128; o > 0; o >>= 1) { if (t < o) red[t] += red[t + o]; __syncthreads(); }
  if (t == 0) stash[0] = red[0];
  __syncthreads();
  red[t] = rsum; __syncthreads();
  for (int o = 128; o > 0; o >>= 1) { if (t < o) red[t] += red[t + o]; __syncthreads(); }
  if (t == 0) stash[1] = red[0];
  __syncthreads();
  red[t] = rmx; __syncthreads();
  for (int o = 128; o > 0; o >>= 1) { if (t < o) red[t] = fmaxf(red[t], red[t + o]); __syncthreads(); }
  if (t == 0) stash[2] = red[0];
  __syncthreads();
  red[t] = sfp; __syncthreads();
  for (int o = 128; o > 0; o >>= 1) { if (t < o) red[t] += red[t + o]; __syncthreads(); }
  if (t == 0) {
    float fwd = stash[0] + PENALTY * ((float)NSF - red[0]);
    float rev = stash[1] * (REV_SCALE / (stash[2] + EPSF));
    out[0] = fwd + rev;
  }
}

extern "C" void kernel_launch(void* const* d_in, const int* in_sizes, int n_in,
                              void* d_out, int out_size, void* d_ws, size_t ws_size,
                              hipStream_t stream) {
  const float* ov  = (const float*)d_in[0];
  const int*   ofc = (const int*)  d_in[1];
  const float* sv  = (const float*)d_in[2];
  const int*   sfc = (const int*)  d_in[3];
  const float* fp  = (const float*)d_in[4];
  float* out = (float*)d_out;

  int NOV = in_sizes[0] / 3;
  int NOF = in_sizes[1] / 3;
  int NSF = in_sizes[3] / 3;
  int NFP = in_sizes[4];
  int nsamp = NSF * NUM_SAMPLES;

  // ws layout: [acc 16KB][gsum 2KB][cnt][cs][cur][float4 arrays]
  char* w = (char*)d_ws;
  float* acc = (float*)w;                       w += ACC_FLOATS * 4;       // 16 KB
  unsigned long long* gsum = (unsigned long long*)w; w += 2048;            // 2 KB
  int*   cnt = (int*)w;                         w += (size_t)NTOTALL * 4;
  size_t zeroBytes = (size_t)(w - (char*)d_ws); // acc + gsum + cnt, contiguous
  int*   cs  = (int*)w;                         w += (size_t)(NTOTALL + 16) * 4;
  int*   cur = (int*)w;                         w += (size_t)NTOTALL * 4;
  float4* ob4    = (float4*)w;  w += (size_t)NOF * 16;
  float4* sb4    = (float4*)w;  w += (size_t)NSF * 16;
  float4* ov4    = (float4*)w;  w += (size_t)NOV * 16;
  float4* sorted = (float4*)w;  w += (size_t)(NOV + NOF) * 16;

  hipMemsetAsync(d_ws, 0, zeroBytes, stream);

  int total = NOF + NSF + NOV;
  hipLaunchKernelGGL(prep_kernel, dim3((total + 255) / 256), dim3(256), 0, stream,
                     ov, ofc, sv, sfc, ob4, sb4, ov4, cnt, NOF, NSF, NOV);

  hipLaunchKernelGGL(scan_kernel, dim3(SCAN_BLOCKS), dim3(256), 0, stream,
                     (const int4*)cnt, gsum, cs, cur);

  hipLaunchKernelGGL(scatter_kernel, dim3((NOV + NOF + 255) / 256), dim3(256), 0, stream,
                     ov4, ob4, cur, sorted, NOV, NOF);

  hipLaunchKernelGGL(query_kernel, dim3(QBLOCKS), dim3(256), 0, stream,
                     fp, sb4, sv, sfc, cs, sorted, acc, out, NSF, NFP, nsamp);
}